// Round 10
// baseline (336.908 us; speedup 1.0000x reference)
//
#include <hip/hip_runtime.h>
#include <hip/hip_bf16.h>
#include <cstdint>
#include <cstddef>

#define BATCH 4
#define SEQ   2048
#define DM    1024
#define NH    16
#define DK    64
#define NELEM ((size_t)BATCH * SEQ * DM)   // 8,388,608
#define NEGF  -3.0e38f
#define QSCALE 0.18033688011112042f        // 0.125 * log2(e)

typedef short  bf16x8 __attribute__((ext_vector_type(8)));
typedef float  f32x4  __attribute__((ext_vector_type(4)));

__device__ __forceinline__ unsigned short f2bf(float f) {
    union { float f; unsigned int u; } c; c.f = f;
    unsigned int u = c.u;
    u += 0x7fffu + ((u >> 16) & 1u);   // RNE
    return (unsigned short)(u >> 16);
}
__device__ __forceinline__ unsigned short t2bf(float f) {   // truncate (P >= 0)
    union { float f; unsigned int u; } c; c.f = f;
    return (unsigned short)(c.u >> 16);
}
__device__ __forceinline__ float exp2_fast(float x) {
#if __has_builtin(__builtin_amdgcn_exp2f)
    return __builtin_amdgcn_exp2f(x);
#else
    return exp2f(x);
#endif
}
// async global->LDS, 16B per lane; LDS dest = wave-uniform base + lane*16
__device__ __forceinline__ void g2l16(const unsigned short* g, unsigned short* l) {
    __builtin_amdgcn_global_load_lds(
        (const __attribute__((address_space(1))) unsigned int*)g,
        (__attribute__((address_space(3))) unsigned int*)l, 16, 0, 0);
}

// ---------------------------------------------------------------------------
// Fused pre-pass: blocks [0,12288) convert q/k/v fp32->bf16; blocks
// [12288,14336) transpose+convert the 4 weight matrices.
// ---------------------------------------------------------------------------
__global__ __launch_bounds__(256)
void cvt_all(const float* __restrict__ q, const float* __restrict__ k,
             const float* __restrict__ v,
             const float* __restrict__ Wq, const float* __restrict__ Wk,
             const float* __restrict__ Wv, const float* __restrict__ Wo,
             unsigned short* __restrict__ out, unsigned short* __restrict__ Wt) {
    const int bx = (int)blockIdx.x;
    if (bx < 12288) {
        const int z = bx >> 12;                // 0..2
        const int bi = bx & 4095;
        const float* src = (z == 0) ? q : (z == 1) ? k : v;
        size_t i = ((size_t)bi * 256 + threadIdx.x) * 8;
        float4 a = *(const float4*)(src + i);
        float4 b = *(const float4*)(src + i + 4);
        unsigned short* o = out + z * NELEM + i;
        ushort4 p0, p1;
        p0.x = f2bf(a.x); p0.y = f2bf(a.y); p0.z = f2bf(a.z); p0.w = f2bf(a.w);
        p1.x = f2bf(b.x); p1.y = f2bf(b.y); p1.z = f2bf(b.z); p1.w = f2bf(b.w);
        *(ushort4*)o = p0; *(ushort4*)(o + 4) = p1;
    } else {
        const int bz = bx - 12288;             // 0..2047
        const int z  = bz >> 9;                // 0..3
        const int bi = bz & 511;
        const float* W = (z == 0) ? Wq : (z == 1) ? Wk : (z == 2) ? Wv : Wo;
        unsigned short* outw = Wt + (size_t)z * DM * DM;
        int gid = bi * 256 + threadIdx.x;
        int n = gid & (DM - 1), k0 = (gid >> 10) << 3;
        ushort4 t0, t1;
        t0.x = f2bf(W[(size_t)(k0 + 0) * DM + n]);
        t0.y = f2bf(W[(size_t)(k0 + 1) * DM + n]);
        t0.z = f2bf(W[(size_t)(k0 + 2) * DM + n]);
        t0.w = f2bf(W[(size_t)(k0 + 3) * DM + n]);
        t1.x = f2bf(W[(size_t)(k0 + 4) * DM + n]);
        t1.y = f2bf(W[(size_t)(k0 + 5) * DM + n]);
        t1.z = f2bf(W[(size_t)(k0 + 6) * DM + n]);
        t1.w = f2bf(W[(size_t)(k0 + 7) * DM + n]);
        *(ushort4*)(outw + (size_t)n * DM + k0) = t0;
        *(ushort4*)(outw + (size_t)n * DM + k0 + 4) = t1;
    }
}

// ---------------------------------------------------------------------------
// GEMM 128x128 tile, 4 waves, BK=64 single-buffered, in-row XOR swizzle
// (R7-verified). Used in the sequential fallback path only.
// ---------------------------------------------------------------------------
template <int MODE>
__global__ __launch_bounds__(256)
void gemm_bt(const unsigned short* __restrict__ A, const unsigned short* __restrict__ Bt,
             const float* __restrict__ bias, void* __restrict__ Cv, float oscale) {
    constexpr int K = 1024, BK = 64;
    constexpr int NN = 1024;
    __shared__ unsigned short As[128 * 64];
    __shared__ unsigned short Bs[128 * 64];

    const int tid  = threadIdx.x;
    const int lane = tid & 63;
    const int wv   = tid >> 6;
    const int wr   = wv >> 1, wc = wv & 1;
    const int lin = (int)(blockIdx.y * gridDim.x + blockIdx.x);   // 512 total
    const int per = lin >> 3;
    const int ty  = ((lin & 7) << 3) | (per >> 3);   // 0..63 M-tile
    const int tx  = per & 7;                         // 0..7  N-tile
    const int m0  = ty * 128, n0 = tx * 128;
    const int lrow = lane & 15, lkg = lane >> 4;

    const int srow = wv * 32 + (lane >> 3);
    const int skg  = ((lane & 7) ^ (lane >> 3)) * 8;
    const unsigned short* Ap = A  + (size_t)(m0 + srow) * K + skg;
    const unsigned short* Bp = Bt + (size_t)(n0 + srow) * K + skg;
    unsigned short* Asw = As + wv * 32 * 64;
    unsigned short* Bsw = Bs + wv * 32 * 64;

    const int kg0 = ((0 + lkg) ^ (lrow & 7)) * 8;
    const int kg1 = ((4 + lkg) ^ (lrow & 7)) * 8;

    f32x4 acc[4][4] = {};

    for (int k0 = 0; k0 < K; k0 += BK) {
        #pragma unroll
        for (int p = 0; p < 4; ++p) {
            g2l16(Ap + (size_t)p * 8 * K + k0, Asw + p * 8 * 64);
            g2l16(Bp + (size_t)p * 8 * K + k0, Bsw + p * 8 * 64);
        }
        __syncthreads();                       // drains vmcnt before barrier

        #pragma unroll
        for (int ks = 0; ks < 2; ++ks) {
            const int kgx = ks ? kg1 : kg0;
            bf16x8 af[4], bfr[4];
            #pragma unroll
            for (int i = 0; i < 4; ++i)
                af[i] = *(bf16x8*)&As[(wr * 64 + i * 16 + lrow) * 64 + kgx];
            #pragma unroll
            for (int j = 0; j < 4; ++j)
                bfr[j] = *(bf16x8*)&Bs[(wc * 64 + j * 16 + lrow) * 64 + kgx];
            #pragma unroll
            for (int i = 0; i < 4; ++i)
                #pragma unroll
                for (int j = 0; j < 4; ++j)
                    acc[i][j] = __builtin_amdgcn_mfma_f32_16x16x32_bf16(af[i], bfr[j], acc[i][j], 0, 0, 0);
        }
        __syncthreads();
    }

    #pragma unroll
    for (int j = 0; j < 4; ++j) {
        int n = n0 + wc * 64 + j * 16 + lrow;
        float bb = bias[n];
        #pragma unroll
        for (int i = 0; i < 4; ++i) {
            #pragma unroll
            for (int r = 0; r < 4; ++r) {
                int m = m0 + wr * 64 + i * 16 + lkg * 4 + r;
                float val = (acc[i][j][r] + bb) * oscale;
                if (MODE == 0) {
                    int b = m >> 11, s = m & (SEQ - 1);
                    int h = n >> 6, d = n & (DK - 1);
                    ((unsigned short*)Cv)[(((size_t)(b * NH + h) * SEQ + s) << 6) + d] = f2bf(val);
                } else if (MODE == 2) {
                    int b = m >> 11, s = m & (SEQ - 1);
                    int h = n >> 6, d = n & (DK - 1);
                    ((unsigned short*)Cv)[((size_t)((b * NH + h) * DK + d) << 11) + s] = f2bf(val);
                } else {
                    ((float*)Cv)[(size_t)m * NN + n] = val;
                }
            }
        }
    }
}

// ---------------------------------------------------------------------------
// Fused QKV: grid (8,64,3), blockIdx.z selects the GEMM. R9-measured:
// 81us for all three projections (635 TF, MfmaUtil 27%, 0 conflicts) —
// the win is occupancy: 1536 blocks -> ~6 resident blocks/CU vs 2.
// ---------------------------------------------------------------------------
__global__ __launch_bounds__(256)
void gemm_qkv(const unsigned short* __restrict__ Abase, const unsigned short* __restrict__ Wt,
              const float* __restrict__ bq, const float* __restrict__ bk,
              const float* __restrict__ bv, unsigned short* __restrict__ Cbase) {
    constexpr int K = 1024, BK = 64;
    __shared__ unsigned short As[128 * 64];
    __shared__ unsigned short Bs[128 * 64];

    const int z = (int)blockIdx.z;
    const unsigned short* A  = Abase + (size_t)z * NELEM;
    const unsigned short* Bt = Wt + (size_t)z * DM * DM;
    const float* bias = (z == 0) ? bq : (z == 1) ? bk : bv;
    unsigned short* Cv = Cbase + (size_t)z * NELEM;
    const float oscale = (z == 0) ? QSCALE : 1.0f;

    const int tid  = threadIdx.x;
    const int lane = tid & 63;
    const int wv   = tid >> 6;
    const int wr   = wv >> 1, wc = wv & 1;
    const int lin = (int)(blockIdx.y * gridDim.x + blockIdx.x);   // 512 per slab
    const int per = lin >> 3;
    const int ty  = ((lin & 7) << 3) | (per >> 3);   // 0..63 M-tile
    const int tx  = per & 7;                         // 0..7  N-tile
    const int m0  = ty * 128, n0 = tx * 128;
    const int lrow = lane & 15, lkg = lane >> 4;

    const int srow = wv * 32 + (lane >> 3);
    const int skg  = ((lane & 7) ^ (lane >> 3)) * 8;
    const unsigned short* Ap = A  + (size_t)(m0 + srow) * K + skg;
    const unsigned short* Bp = Bt + (size_t)(n0 + srow) * K + skg;
    unsigned short* Asw = As + wv * 32 * 64;
    unsigned short* Bsw = Bs + wv * 32 * 64;

    const int kg0 = ((0 + lkg) ^ (lrow & 7)) * 8;
    const int kg1 = ((4 + lkg) ^ (lrow & 7)) * 8;

    f32x4 acc[4][4] = {};

    for (int k0 = 0; k0 < K; k0 += BK) {
        #pragma unroll
        for (int p = 0; p < 4; ++p) {
            g2l16(Ap + (size_t)p * 8 * K + k0, Asw + p * 8 * 64);
            g2l16(Bp + (size_t)p * 8 * K + k0, Bsw + p * 8 * 64);
        }
        __syncthreads();

        #pragma unroll
        for (int ks = 0; ks < 2; ++ks) {
            const int kgx = ks ? kg1 : kg0;
            bf16x8 af[4], bfr[4];
            #pragma unroll
            for (int i = 0; i < 4; ++i)
                af[i] = *(bf16x8*)&As[(wr * 64 + i * 16 + lrow) * 64 + kgx];
            #pragma unroll
            for (int j = 0; j < 4; ++j)
                bfr[j] = *(bf16x8*)&Bs[(wc * 64 + j * 16 + lrow) * 64 + kgx];
            #pragma unroll
            for (int i = 0; i < 4; ++i)
                #pragma unroll
                for (int j = 0; j < 4; ++j)
                    acc[i][j] = __builtin_amdgcn_mfma_f32_16x16x32_bf16(af[i], bfr[j], acc[i][j], 0, 0, 0);
        }
        __syncthreads();
    }

    #pragma unroll
    for (int j = 0; j < 4; ++j) {
        int n = n0 + wc * 64 + j * 16 + lrow;
        float bb = bias[n];
        #pragma unroll
        for (int i = 0; i < 4; ++i) {
            #pragma unroll
            for (int r = 0; r < 4; ++r) {
                int m = m0 + wr * 64 + i * 16 + lkg * 4 + r;
                float val = (acc[i][j][r] + bb) * oscale;
                int b = m >> 11, s = m & (SEQ - 1);
                int h = n >> 6, d = n & (DK - 1);
                if (z == 2) {   // V stored transposed [B,H,DK,S]
                    Cv[((size_t)((b * NH + h) * DK + d) << 11) + s] = f2bf(val);
                } else {        // Q,K stored [B,H,S,DK]
                    Cv[(((size_t)(b * NH + h) * SEQ + s) << 6) + d] = f2bf(val);
                }
            }
        }
    }
}

// ---------------------------------------------------------------------------
// Wo projection, 64x128 tile (NEW): grid (8,128) = 1024 blocks -> 4 resident
// blocks/CU (was 2 at 128x128 / 512 blocks) — applying the occupancy
// mechanism gemm_qkv just proved (2x per-GEMM rate at >4 blocks/CU).
// Inner loop = R7-proven pattern: BK=64 single-buffered, chunked g2l16
// staging (chunk = 8 rows x 64k), in-row XOR swizzle pair (chunk-row
// arithmetic identical since 16 = 0 mod 8). 4 waves x 64x32 output strip,
// acc[4][2] = 32 regs. LDS 24KB. Extra B-panel re-reads are L2-resident
// per XCD (2MB < 4MB).
// ---------------------------------------------------------------------------
__global__ __launch_bounds__(256)
void gemm_wo(const unsigned short* __restrict__ A, const unsigned short* __restrict__ Bt,
             const float* __restrict__ bias, float* __restrict__ C) {
    constexpr int K = 1024, BK = 64;
    __shared__ unsigned short As[64 * 64];
    __shared__ unsigned short Bs[128 * 64];

    const int tid  = threadIdx.x;
    const int lane = tid & 63;
    const int wv   = tid >> 6;          // 0..3 — owns output cols [wv*32,+32)
    const int lrow = lane & 15, lkg = lane >> 4;

    const int lin = (int)(blockIdx.y * gridDim.x + blockIdx.x);   // 1024 total
    const int xcd = lin & 7;
    const int per = lin >> 3;                 // 0..127
    const int ty  = xcd * 16 + (per >> 3);    // 0..127 M-tile (XCD-contiguous)
    const int tx  = per & 7;                  // 0..7   N-tile
    const int m0  = ty * 64, n0 = tx * 128;

    // staging lane map (chunk = 8 rows x 64k): lane l -> row (l>>3),
    // in-row source 16B-seg (l&7)^(l>>3); LDS dest linear.
    const int crow = lane >> 3;
    const int cseg = ((lane & 7) ^ (lane >> 3)) * 8;
    // A: wave wv stages rows [wv*16, wv*16+16) (2 chunks)
    const unsigned short* ApA = A + (size_t)(m0 + wv * 16 + crow) * K + cseg;
    // B: wave wv stages rows [wv*32, wv*32+32) (4 chunks)
    const unsigned short* BpB = Bt + (size_t)(n0 + wv * 32 + crow) * K + cseg;
    unsigned short* Asw = As + wv * 16 * 64;
    unsigned short* Bsw = Bs + wv * 32 * 64;

    const int kg0 = ((0 + lkg) ^ (lrow & 7)) * 8;
    const int kg1 = ((4 + lkg) ^ (lrow & 7)) * 8;

    f32x4 acc[4][2] = {};

    for (int k0 = 0; k0 < K; k0 += BK) {
        g2l16(ApA + k0, Asw);
        g2l16(ApA + (size_t)8 * K + k0, Asw + 8 * 64);
        #pragma unroll
        for (int p = 0; p < 4; ++p)
            g2l16(BpB + (size_t)p * 8 * K + k0, Bsw + p * 8 * 64);
        __syncthreads();                       // drains vmcnt before barrier

        #pragma unroll
        for (int ks = 0; ks < 2; ++ks) {
            const int kgx = ks ? kg1 : kg0;
            bf16x8 af[4], bfr[2];
            #pragma unroll
            for (int i = 0; i < 4; ++i)
                af[i] = *(bf16x8*)&As[(i * 16 + lrow) * 64 + kgx];
            #pragma unroll
            for (int j = 0; j < 2; ++j)
                bfr[j] = *(bf16x8*)&Bs[(wv * 32 + j * 16 + lrow) * 64 + kgx];
            #pragma unroll
            for (int i = 0; i < 4; ++i)
                #pragma unroll
                for (int j = 0; j < 2; ++j)
                    acc[i][j] = __builtin_amdgcn_mfma_f32_16x16x32_bf16(af[i], bfr[j], acc[i][j], 0, 0, 0);
        }
        __syncthreads();
    }

    #pragma unroll
    for (int j = 0; j < 2; ++j) {
        int n = n0 + wv * 32 + j * 16 + lrow;
        float bb = bias[n];
        #pragma unroll
        for (int i = 0; i < 4; ++i) {
            #pragma unroll
            for (int r = 0; r < 4; ++r) {
                int m = m0 + i * 16 + lkg * 4 + r;
                C[(size_t)m * DM + n] = acc[i][j][r] + bb;
            }
        }
    }
}

// ---------------------------------------------------------------------------
// MFMA flash attention (causal) — unchanged (71us, 459K conflicts).
// Q pre-scaled by QSCALE. Q,K: [B,H,S,DK]. V: [B,H,DK,S]. Out: [B,S,DM].
// ---------------------------------------------------------------------------
__global__ __launch_bounds__(256)
void attn_mfma(const unsigned short* __restrict__ Qg,
               const unsigned short* __restrict__ Kg,
               const unsigned short* __restrict__ Vg,
               unsigned short* __restrict__ Out) {
    __shared__ unsigned short Kl[2][4096];   // 2 bufs x 8 chunks x 512 shorts
    __shared__ unsigned short Vl[2][4096];
    __shared__ unsigned short Pl[8192];      // 4 waves x 4 chunks x 512

    const int tid  = threadIdx.x;
    const int lane = tid & 63;
    const int wv   = tid >> 6;
    const int col  = lane & 15, quad = lane >> 4;
    const int bh   = blockIdx.x;
    const int qt   = (int)(gridDim.y - 1 - blockIdx.y);   // heavy tiles first
    const int q0   = qt * 128 + wv * 32;
    const int qhi  = q0 + 31;
    const int b    = bh >> 4, h = bh & 15;

    const unsigned short* Qb = Qg + (size_t)bh * SEQ * DK;
    const unsigned short* Kb = Kg + (size_t)bh * SEQ * DK;
    const unsigned short* Vb = Vg + (size_t)bh * DK * SEQ;

    // Q fragments (A-layout), once from global
    bf16x8 aq[2][2];
    #pragma unroll
    for (int mt = 0; mt < 2; ++mt)
        #pragma unroll
        for (int ks = 0; ks < 2; ++ks)
            aq[mt][ks] = *(const bf16x8*)(Qb + (size_t)(q0 + mt * 16 + col) * DK + ks * 32 + quad * 8);

    f32x4 oacc[2][4] = {};
    float lrow[2][4] = {};

    const unsigned short* Kp = Kb + (size_t)(wv * 16 + col) * DK + quad * 8;
    const unsigned short* Vp = Vb + (size_t)(wv * 16 + col) * SEQ + quad * 8;
    unsigned short* Plw  = Pl + wv * 2048;

    const int psw = ((quad >> 1) << 3) | ((col >> 3) << 4);
    const int rsw = (((lane >> 3) & 1) << 3) | (((lane >> 4) & 1) << 4);
    int pq[4];
    #pragma unroll
    for (int r = 0; r < 4; ++r)
        pq[r] = ((quad * 4 + r) * 8) ^ psw;

    int pb[4];
    #pragma unroll
    for (int kg = 0; kg < 4; ++kg)
        pb[kg] = (kg >> 1) * 512 + ((kg & 1) * 2 + (col >> 3)) * 128 + (col & 7);

    const int nfull = qt * 2;
    const int ntot  = nfull + 2;

    // prologue: stage tile 0 into buffer 0 (4 loads in flight)
    {
        unsigned short* kd = &Kl[0][wv * 1024];
        unsigned short* vd = &Vl[0][wv * 1024];
        g2l16(Kp, kd);
        g2l16(Kp + 32, kd + 512);
        g2l16(Vp, vd);
        g2l16(Vp + 32, vd + 512);
    }

    for (int kt = 0; kt < ntot; ++kt) {
        const int cur = kt & 1;
        const int kbase = kt * 64;

        if (kt + 1 < ntot) {
            const size_t nb = (size_t)(kt + 1) * 64;
            unsigned short* kd = &Kl[cur ^ 1][wv * 1024];
            unsigned short* vd = &Vl[cur ^ 1][wv * 1024];
            g2l16(Kp + nb * DK, kd);
            g2l16(Kp + nb * DK + 32, kd + 512);
            g2l16(Vp + nb, vd);
            g2l16(Vp + nb + 32, vd + 512);
            asm volatile("s_waitcnt vmcnt(4)" ::: "memory");
        } else {
            asm volatile("s_waitcnt vmcnt(0)" ::: "memory");
        }
        __builtin_amdgcn_sched_barrier(0);
        __builtin_amdgcn_s_barrier();
        __builtin_amdgcn_sched_barrier(0);

        if (kbase <= qhi) {                       // wave-uniform: skip fully-masked tiles
            const unsigned short* Kc = &Kl[cur][0];
            const unsigned short* Vc = &Vl[cur][0];

            bf16x8 bk[4][2];
            #pragma unroll
            for (int kg = 0; kg < 4; ++kg)
                #pragma unroll
                for (int ks = 0; ks < 2; ++ks)
                    bk[kg][ks] = *(const bf16x8*)&Kc[(kg * 2 + ks) * 512 + lane * 8];

            f32x4 sc[2][4];
            __builtin_amdgcn_s_setprio(1);
            #pragma unroll
            for (int mt = 0; mt < 2; ++mt)
                #pragma unroll
                for (int kg = 0; kg < 4; ++kg) {
                    f32x4 z = {};
                    z = __builtin_amdgcn_mfma_f32_16x16x32_bf16(aq[mt][0], bk[kg][0], z, 0, 0, 0);
                    sc[mt][kg] = __builtin_amdgcn_mfma_f32_16x16x32_bf16(aq[mt][1], bk[kg][1], z, 0, 0, 0);
                }
            __builtin_amdgcn_s_setprio(0);

            if (kt >= nfull) {                    // diagonal tiles: causal mask
                #pragma unroll
                for (int mt = 0; mt < 2; ++mt)
                    #pragma unroll
                    for (int kg = 0; kg < 4; ++kg)
                        #pragma unroll
                        for (int r = 0; r < 4; ++r) {
                            int key = kbase + kg * 16 + col;
                            int qr  = q0 + mt * 16 + quad * 4 + r;
                            if (key > qr) sc[mt][kg][r] = NEGF;
                        }
            }

            #pragma unroll
            for (int mt = 0; mt < 2; ++mt)
                #pragma unroll
                for (int kg = 0; kg < 4; ++kg)
                    #pragma unroll
                    for (int r = 0; r < 4; ++r)
                        sc[mt][kg][r] = exp2_fast(sc[mt][kg][r]);

            #pragma unroll
            for (int mt = 0; mt < 2; ++mt)
                #pragma unroll
                for (int r = 0; r < 4; ++r)
                    lrow[mt][r] += (sc[mt][0][r] + sc[mt][1][r]) +
                                   (sc[mt][2][r] + sc[mt][3][r]);

            #pragma unroll
            for (int mt = 0; mt < 2; ++mt)
                #pragma unroll
                for (int kg = 0; kg < 4; ++kg)
                    #pragma unroll
                    for (int r = 0; r < 4; ++r)
                        Plw[mt * 1024 + pb[kg] + pq[r]] = t2bf(sc[mt][kg][r]);

            bf16x8 ap[2][2];
            #pragma unroll
            for (int mt = 0; mt < 2; ++mt)
                #pragma unroll
                for (int ks = 0; ks < 2; ++ks)
                    ap[mt][ks] = *(const bf16x8*)&Plw[(mt * 2 + ks) * 512 + ((lane * 8) ^ rsw)];

            __builtin_amdgcn_s_setprio(1);
            #pragma unroll
            for (int dc = 0; dc < 4; ++dc)
                #pragma unroll
                for (int ks = 0; ks < 2; ++ks) {
                    bf16x8 bv = *(const bf16x8*)&Vc[(dc * 2 + ks) * 512 + lane * 8];
                    oacc[0][dc] = __builtin_amdgcn_mfma_f32_16x16x32_bf16(ap[0][ks], bv, oacc[0][dc], 0, 0, 0);
                    oacc[1][dc] = __builtin_amdgcn_mfma_f32_16x16x32_bf16(ap[1][ks], bv, oacc[1][dc], 0, 0, 0);
                }
            __builtin_amdgcn_s_setprio(0);
        }
        asm volatile("s_waitcnt lgkmcnt(0)" ::: "memory");
        __builtin_amdgcn_sched_barrier(0);
        __builtin_amdgcn_s_barrier();
        __builtin_amdgcn_sched_barrier(0);
    }

    // single cross-lane reduction of row sums (rows live across the 16 col-lanes)
    #pragma unroll
    for (int d = 1; d < 16; d <<= 1)
        #pragma unroll
        for (int mt = 0; mt < 2; ++mt)
            #pragma unroll
            for (int r = 0; r < 4; ++r)
                lrow[mt][r] += __shfl_xor(lrow[mt][r], d);

    // epilogue: normalize, transpose via wave-private LDS, coalesced 16B stores
    unsigned short* Ol = Plw;                 // 2048 shorts = 32 rows x 64
    #pragma unroll
    for (int mt = 0; mt < 2; ++mt)
        #pragma unroll
        for (int r = 0; r < 4; ++r) {
            float inv = 1.0f / lrow[mt][r];
            int orow = (mt * 16 + quad * 4 + r) * 64;
            #pragma unroll
            for (int dc = 0; dc < 4; ++dc)
                Ol[orow + dc * 16 + col] = f2bf(oacc[mt][dc][r] * inv);
        }
    const int orw = lane >> 1, ohalf = lane & 1;
    unsigned short* og = Out + (size_t)(b * SEQ + q0 + orw) * DM + h * DK + ohalf * 32;
    #pragma unroll
    for (int s = 0; s < 4; ++s)
        *(uint4*)(og + s * 8) = *(const uint4*)&Ol[orw * 64 + ohalf * 32 + s * 8];
}

extern "C" void kernel_launch(void* const* d_in, const int* in_sizes, int n_in,
                              void* d_out, int out_size, void* d_ws, size_t ws_size,
                              hipStream_t stream) {
    // setup_inputs order: query, value, key, Wq, bq, Wk, bk, Wv, bv, Wo, bo
    const float* query = (const float*)d_in[0];
    const float* value = (const float*)d_in[1];
    const float* key   = (const float*)d_in[2];
    const float* Wq = (const float*)d_in[3];
    const float* bq = (const float*)d_in[4];
    const float* Wk = (const float*)d_in[5];
    const float* bk = (const float*)d_in[6];
    const float* Wv = (const float*)d_in[7];
    const float* bv = (const float*)d_in[8];
    const float* Wo = (const float*)d_in[9];
    const float* bo = (const float*)d_in[10];

    // de-aliased layout: 6 activation regions + 4 weight matrices
    const size_t need = ((size_t)6 * NELEM + (size_t)4 * DM * DM) * sizeof(unsigned short);
    const bool bigws = ws_size >= need;

    if (bigws) {
        unsigned short* W0 = (unsigned short*)d_ws;        // qbf/kbf/vbf, then attn-out
        unsigned short* W3 = W0 + 3 * NELEM;               // qws,kws,vws (contiguous)
        unsigned short* Wt = W0 + 6 * NELEM;
        unsigned short* Wto = Wt + 3 * (size_t)DM * DM;

        cvt_all<<<dim3(14336), 256, 0, stream>>>(query, key, value, Wq, Wk, Wv, Wo, W0, Wt);

        // fused QKV: one launch, 3 z-slabs of the proven 128^2 structure
        gemm_qkv<<<dim3(8, 64, 3), 256, 0, stream>>>(W0, Wt, bq, bk, bv, W3);

        attn_mfma<<<dim3(BATCH * NH, SEQ / 128), 256, 0, stream>>>(
            W3, W3 + NELEM, W3 + 2 * NELEM, W0);

        // Wo at 64x128 tiles: 1024 blocks -> 4 resident blocks/CU
        gemm_wo<<<dim3(8, 128), 256, 0, stream>>>(W0, Wto, bo, (float*)d_out);
    } else {
        // fallback: exact R7 sequential structure (known-good 330us)
        unsigned short* R0 = (unsigned short*)d_ws;
        unsigned short* R1 = R0 + NELEM;
        unsigned short* R2 = R1 + NELEM;
        unsigned short* R3 = R2 + NELEM;
        unsigned short* Wt = R3 + NELEM;
        unsigned short* qbf = R0, *kbf = R1, *vbf = R2;
        unsigned short* qws = R3, *kws = R0, *vws = R1, *aws = R2;
        unsigned short* Wtq = Wt, *Wtk = Wt + (size_t)DM * DM,
                      * Wtv = Wt + 2 * (size_t)DM * DM, *Wto = Wt + 3 * (size_t)DM * DM;

        cvt_all<<<dim3(14336), 256, 0, stream>>>(query, key, value, Wq, Wk, Wv, Wo, R0, Wt);

        dim3 gg(8, 64);
        gemm_bt<0><<<gg, 256, 0, stream>>>(qbf, Wtq, bq, qws, QSCALE);
        gemm_bt<0><<<gg, 256, 0, stream>>>(kbf, Wtk, bk, kws, 1.0f);
        gemm_bt<2><<<gg, 256, 0, stream>>>(vbf, Wtv, bv, vws, 1.0f);

        attn_mfma<<<dim3(BATCH * NH, SEQ / 128), 256, 0, stream>>>(qws, kws, vws, aws);

        gemm_bt<1><<<gg, 256, 0, stream>>>(aws, Wto, bo, d_out, 1.0f);
    }
}

// Round 11
// 328.778 us; speedup vs baseline: 1.0247x; 1.0247x over previous
//
#include <hip/hip_runtime.h>
#include <hip/hip_bf16.h>
#include <cstdint>
#include <cstddef>

#define BATCH 4
#define SEQ   2048
#define DM    1024
#define NH    16
#define DK    64
#define NELEM ((size_t)BATCH * SEQ * DM)   // 8,388,608
#define NEGF  -3.0e38f
#define QSCALE 0.18033688011112042f        // 0.125 * log2(e)

typedef short  bf16x8 __attribute__((ext_vector_type(8)));
typedef float  f32x4  __attribute__((ext_vector_type(4)));

__device__ __forceinline__ unsigned short f2bf(float f) {
    union { float f; unsigned int u; } c; c.f = f;
    unsigned int u = c.u;
    u += 0x7fffu + ((u >> 16) & 1u);   // RNE
    return (unsigned short)(u >> 16);
}
__device__ __forceinline__ unsigned short t2bf(float f) {   // truncate (P >= 0)
    union { float f; unsigned int u; } c; c.f = f;
    return (unsigned short)(c.u >> 16);
}
__device__ __forceinline__ float exp2_fast(float x) {
#if __has_builtin(__builtin_amdgcn_exp2f)
    return __builtin_amdgcn_exp2f(x);
#else
    return exp2f(x);
#endif
}
// async global->LDS, 16B per lane; LDS dest = wave-uniform base + lane*16
__device__ __forceinline__ void g2l16(const unsigned short* g, unsigned short* l) {
    __builtin_amdgcn_global_load_lds(
        (const __attribute__((address_space(1))) unsigned int*)g,
        (__attribute__((address_space(3))) unsigned int*)l, 16, 0, 0);
}

// ---------------------------------------------------------------------------
// Fused pre-pass: blocks [0,12288) convert q/k/v fp32->bf16; blocks
// [12288,14336) transpose+convert the 4 weight matrices.
// ---------------------------------------------------------------------------
__global__ __launch_bounds__(256)
void cvt_all(const float* __restrict__ q, const float* __restrict__ k,
             const float* __restrict__ v,
             const float* __restrict__ Wq, const float* __restrict__ Wk,
             const float* __restrict__ Wv, const float* __restrict__ Wo,
             unsigned short* __restrict__ out, unsigned short* __restrict__ Wt) {
    const int bx = (int)blockIdx.x;
    if (bx < 12288) {
        const int z = bx >> 12;                // 0..2
        const int bi = bx & 4095;
        const float* src = (z == 0) ? q : (z == 1) ? k : v;
        size_t i = ((size_t)bi * 256 + threadIdx.x) * 8;
        float4 a = *(const float4*)(src + i);
        float4 b = *(const float4*)(src + i + 4);
        unsigned short* o = out + z * NELEM + i;
        ushort4 p0, p1;
        p0.x = f2bf(a.x); p0.y = f2bf(a.y); p0.z = f2bf(a.z); p0.w = f2bf(a.w);
        p1.x = f2bf(b.x); p1.y = f2bf(b.y); p1.z = f2bf(b.z); p1.w = f2bf(b.w);
        *(ushort4*)o = p0; *(ushort4*)(o + 4) = p1;
    } else {
        const int bz = bx - 12288;             // 0..2047
        const int z  = bz >> 9;                // 0..3
        const int bi = bz & 511;
        const float* W = (z == 0) ? Wq : (z == 1) ? Wk : (z == 2) ? Wv : Wo;
        unsigned short* outw = Wt + (size_t)z * DM * DM;
        int gid = bi * 256 + threadIdx.x;
        int n = gid & (DM - 1), k0 = (gid >> 10) << 3;
        ushort4 t0, t1;
        t0.x = f2bf(W[(size_t)(k0 + 0) * DM + n]);
        t0.y = f2bf(W[(size_t)(k0 + 1) * DM + n]);
        t0.z = f2bf(W[(size_t)(k0 + 2) * DM + n]);
        t0.w = f2bf(W[(size_t)(k0 + 3) * DM + n]);
        t1.x = f2bf(W[(size_t)(k0 + 4) * DM + n]);
        t1.y = f2bf(W[(size_t)(k0 + 5) * DM + n]);
        t1.z = f2bf(W[(size_t)(k0 + 6) * DM + n]);
        t1.w = f2bf(W[(size_t)(k0 + 7) * DM + n]);
        *(ushort4*)(outw + (size_t)n * DM + k0) = t0;
        *(ushort4*)(outw + (size_t)n * DM + k0 + 4) = t1;
    }
}

// ---------------------------------------------------------------------------
// Fused QKV: grid (8,64,3), blockIdx.z selects the GEMM (R9-measured 81us,
// 635 TF, 0 conflicts — occupancy win: 1536 blocks -> ~5 resident/CU).
// Per-GEMM output pointers are now explicit so K/V projections can land in
// d_out-as-scratch (Q->R3, K->D0, V->D1): the whole pipeline then fits the
// sequential path's 75MB workspace footprint — testing the hypothesis that
// the fused builds' ~100us phantom residual is footprint-proportional
// (harness reset/memset traffic), since all small-footprint builds
// reconcile and all 104MB builds don't.
// ---------------------------------------------------------------------------
__global__ __launch_bounds__(256)
void gemm_qkv(const unsigned short* __restrict__ Abase, const unsigned short* __restrict__ Wt,
              const float* __restrict__ bq, const float* __restrict__ bk,
              const float* __restrict__ bv,
              unsigned short* __restrict__ Cq, unsigned short* __restrict__ Ck,
              unsigned short* __restrict__ Cvv) {
    constexpr int K = 1024, BK = 64;
    __shared__ unsigned short As[128 * 64];
    __shared__ unsigned short Bs[128 * 64];

    const int z = (int)blockIdx.z;
    const unsigned short* A  = Abase + (size_t)z * NELEM;
    const unsigned short* Bt = Wt + (size_t)z * DM * DM;
    const float* bias = (z == 0) ? bq : (z == 1) ? bk : bv;
    unsigned short* Cv = (z == 0) ? Cq : (z == 1) ? Ck : Cvv;
    const float oscale = (z == 0) ? QSCALE : 1.0f;

    const int tid  = threadIdx.x;
    const int lane = tid & 63;
    const int wv   = tid >> 6;
    const int wr   = wv >> 1, wc = wv & 1;
    const int lin = (int)(blockIdx.y * gridDim.x + blockIdx.x);   // 512 per slab
    const int per = lin >> 3;
    const int ty  = ((lin & 7) << 3) | (per >> 3);   // 0..63 M-tile
    const int tx  = per & 7;                         // 0..7  N-tile
    const int m0  = ty * 128, n0 = tx * 128;
    const int lrow = lane & 15, lkg = lane >> 4;

    const int srow = wv * 32 + (lane >> 3);
    const int skg  = ((lane & 7) ^ (lane >> 3)) * 8;
    const unsigned short* Ap = A  + (size_t)(m0 + srow) * K + skg;
    const unsigned short* Bp = Bt + (size_t)(n0 + srow) * K + skg;
    unsigned short* Asw = As + wv * 32 * 64;
    unsigned short* Bsw = Bs + wv * 32 * 64;

    const int kg0 = ((0 + lkg) ^ (lrow & 7)) * 8;
    const int kg1 = ((4 + lkg) ^ (lrow & 7)) * 8;

    f32x4 acc[4][4] = {};

    for (int k0 = 0; k0 < K; k0 += BK) {
        #pragma unroll
        for (int p = 0; p < 4; ++p) {
            g2l16(Ap + (size_t)p * 8 * K + k0, Asw + p * 8 * 64);
            g2l16(Bp + (size_t)p * 8 * K + k0, Bsw + p * 8 * 64);
        }
        __syncthreads();

        #pragma unroll
        for (int ks = 0; ks < 2; ++ks) {
            const int kgx = ks ? kg1 : kg0;
            bf16x8 af[4], bfr[4];
            #pragma unroll
            for (int i = 0; i < 4; ++i)
                af[i] = *(bf16x8*)&As[(wr * 64 + i * 16 + lrow) * 64 + kgx];
            #pragma unroll
            for (int j = 0; j < 4; ++j)
                bfr[j] = *(bf16x8*)&Bs[(wc * 64 + j * 16 + lrow) * 64 + kgx];
            #pragma unroll
            for (int i = 0; i < 4; ++i)
                #pragma unroll
                for (int j = 0; j < 4; ++j)
                    acc[i][j] = __builtin_amdgcn_mfma_f32_16x16x32_bf16(af[i], bfr[j], acc[i][j], 0, 0, 0);
        }
        __syncthreads();
    }

    #pragma unroll
    for (int j = 0; j < 4; ++j) {
        int n = n0 + wc * 64 + j * 16 + lrow;
        float bb = bias[n];
        #pragma unroll
        for (int i = 0; i < 4; ++i) {
            #pragma unroll
            for (int r = 0; r < 4; ++r) {
                int m = m0 + wr * 64 + i * 16 + lkg * 4 + r;
                float val = (acc[i][j][r] + bb) * oscale;
                int b = m >> 11, s = m & (SEQ - 1);
                int h = n >> 6, d = n & (DK - 1);
                if (z == 2) {   // V stored transposed [B,H,DK,S]
                    Cv[((size_t)((b * NH + h) * DK + d) << 11) + s] = f2bf(val);
                } else {        // Q,K stored [B,H,S,DK]
                    Cv[(((size_t)(b * NH + h) * SEQ + s) << 6) + d] = f2bf(val);
                }
            }
        }
    }
}

// ---------------------------------------------------------------------------
// Wo projection, 64x128 tile (R10-verified): 1024 blocks -> 4 resident
// blocks/CU. Inner loop = proven BK=64 + in-row XOR swizzle pattern.
// Reads bf16 attn-out, writes final f32 directly to d_out.
// ---------------------------------------------------------------------------
__global__ __launch_bounds__(256)
void gemm_wo(const unsigned short* __restrict__ A, const unsigned short* __restrict__ Bt,
             const float* __restrict__ bias, float* __restrict__ C) {
    constexpr int K = 1024, BK = 64;
    __shared__ unsigned short As[64 * 64];
    __shared__ unsigned short Bs[128 * 64];

    const int tid  = threadIdx.x;
    const int lane = tid & 63;
    const int wv   = tid >> 6;          // 0..3 — owns output cols [wv*32,+32)
    const int lrow = lane & 15, lkg = lane >> 4;

    const int lin = (int)(blockIdx.y * gridDim.x + blockIdx.x);   // 1024 total
    const int xcd = lin & 7;
    const int per = lin >> 3;                 // 0..127
    const int ty  = xcd * 16 + (per >> 3);    // 0..127 M-tile (XCD-contiguous)
    const int tx  = per & 7;                  // 0..7   N-tile
    const int m0  = ty * 64, n0 = tx * 128;

    const int crow = lane >> 3;
    const int cseg = ((lane & 7) ^ (lane >> 3)) * 8;
    const unsigned short* ApA = A + (size_t)(m0 + wv * 16 + crow) * K + cseg;
    const unsigned short* BpB = Bt + (size_t)(n0 + wv * 32 + crow) * K + cseg;
    unsigned short* Asw = As + wv * 16 * 64;
    unsigned short* Bsw = Bs + wv * 32 * 64;

    const int kg0 = ((0 + lkg) ^ (lrow & 7)) * 8;
    const int kg1 = ((4 + lkg) ^ (lrow & 7)) * 8;

    f32x4 acc[4][2] = {};

    for (int k0 = 0; k0 < K; k0 += BK) {
        g2l16(ApA + k0, Asw);
        g2l16(ApA + (size_t)8 * K + k0, Asw + 8 * 64);
        #pragma unroll
        for (int p = 0; p < 4; ++p)
            g2l16(BpB + (size_t)p * 8 * K + k0, Bsw + p * 8 * 64);
        __syncthreads();                       // drains vmcnt before barrier

        #pragma unroll
        for (int ks = 0; ks < 2; ++ks) {
            const int kgx = ks ? kg1 : kg0;
            bf16x8 af[4], bfr[2];
            #pragma unroll
            for (int i = 0; i < 4; ++i)
                af[i] = *(bf16x8*)&As[(i * 16 + lrow) * 64 + kgx];
            #pragma unroll
            for (int j = 0; j < 2; ++j)
                bfr[j] = *(bf16x8*)&Bs[(wv * 32 + j * 16 + lrow) * 64 + kgx];
            #pragma unroll
            for (int i = 0; i < 4; ++i)
                #pragma unroll
                for (int j = 0; j < 2; ++j)
                    acc[i][j] = __builtin_amdgcn_mfma_f32_16x16x32_bf16(af[i], bfr[j], acc[i][j], 0, 0, 0);
        }
        __syncthreads();
    }

    #pragma unroll
    for (int j = 0; j < 2; ++j) {
        int n = n0 + wv * 32 + j * 16 + lrow;
        float bb = bias[n];
        #pragma unroll
        for (int i = 0; i < 4; ++i) {
            #pragma unroll
            for (int r = 0; r < 4; ++r) {
                int m = m0 + i * 16 + lkg * 4 + r;
                C[(size_t)m * DM + n] = acc[i][j][r] + bb;
            }
        }
    }
}

// ---------------------------------------------------------------------------
// MFMA flash attention (causal) — unchanged (71us, 459K conflicts).
// Q pre-scaled by QSCALE. Q,K: [B,H,S,DK]. V: [B,H,DK,S]. Out: [B,S,DM].
// ---------------------------------------------------------------------------
__global__ __launch_bounds__(256)
void attn_mfma(const unsigned short* __restrict__ Qg,
               const unsigned short* __restrict__ Kg,
               const unsigned short* __restrict__ Vg,
               unsigned short* __restrict__ Out) {
    __shared__ unsigned short Kl[2][4096];   // 2 bufs x 8 chunks x 512 shorts
    __shared__ unsigned short Vl[2][4096];
    __shared__ unsigned short Pl[8192];      // 4 waves x 4 chunks x 512

    const int tid  = threadIdx.x;
    const int lane = tid & 63;
    const int wv   = tid >> 6;
    const int col  = lane & 15, quad = lane >> 4;
    const int bh   = blockIdx.x;
    const int qt   = (int)(gridDim.y - 1 - blockIdx.y);   // heavy tiles first
    const int q0   = qt * 128 + wv * 32;
    const int qhi  = q0 + 31;
    const int b    = bh >> 4, h = bh & 15;

    const unsigned short* Qb = Qg + (size_t)bh * SEQ * DK;
    const unsigned short* Kb = Kg + (size_t)bh * SEQ * DK;
    const unsigned short* Vb = Vg + (size_t)bh * DK * SEQ;

    // Q fragments (A-layout), once from global
    bf16x8 aq[2][2];
    #pragma unroll
    for (int mt = 0; mt < 2; ++mt)
        #pragma unroll
        for (int ks = 0; ks < 2; ++ks)
            aq[mt][ks] = *(const bf16x8*)(Qb + (size_t)(q0 + mt * 16 + col) * DK + ks * 32 + quad * 8);

    f32x4 oacc[2][4] = {};
    float lrow[2][4] = {};

    const unsigned short* Kp = Kb + (size_t)(wv * 16 + col) * DK + quad * 8;
    const unsigned short* Vp = Vb + (size_t)(wv * 16 + col) * SEQ + quad * 8;
    unsigned short* Plw  = Pl + wv * 2048;

    const int psw = ((quad >> 1) << 3) | ((col >> 3) << 4);
    const int rsw = (((lane >> 3) & 1) << 3) | (((lane >> 4) & 1) << 4);
    int pq[4];
    #pragma unroll
    for (int r = 0; r < 4; ++r)
        pq[r] = ((quad * 4 + r) * 8) ^ psw;

    int pb[4];
    #pragma unroll
    for (int kg = 0; kg < 4; ++kg)
        pb[kg] = (kg >> 1) * 512 + ((kg & 1) * 2 + (col >> 3)) * 128 + (col & 7);

    const int nfull = qt * 2;
    const int ntot  = nfull + 2;

    // prologue: stage tile 0 into buffer 0 (4 loads in flight)
    {
        unsigned short* kd = &Kl[0][wv * 1024];
        unsigned short* vd = &Vl[0][wv * 1024];
        g2l16(Kp, kd);
        g2l16(Kp + 32, kd + 512);
        g2l16(Vp, vd);
        g2l16(Vp + 32, vd + 512);
    }

    for (int kt = 0; kt < ntot; ++kt) {
        const int cur = kt & 1;
        const int kbase = kt * 64;

        if (kt + 1 < ntot) {
            const size_t nb = (size_t)(kt + 1) * 64;
            unsigned short* kd = &Kl[cur ^ 1][wv * 1024];
            unsigned short* vd = &Vl[cur ^ 1][wv * 1024];
            g2l16(Kp + nb * DK, kd);
            g2l16(Kp + nb * DK + 32, kd + 512);
            g2l16(Vp + nb, vd);
            g2l16(Vp + nb + 32, vd + 512);
            asm volatile("s_waitcnt vmcnt(4)" ::: "memory");
        } else {
            asm volatile("s_waitcnt vmcnt(0)" ::: "memory");
        }
        __builtin_amdgcn_sched_barrier(0);
        __builtin_amdgcn_s_barrier();
        __builtin_amdgcn_sched_barrier(0);

        if (kbase <= qhi) {                       // wave-uniform: skip fully-masked tiles
            const unsigned short* Kc = &Kl[cur][0];
            const unsigned short* Vc = &Vl[cur][0];

            bf16x8 bk[4][2];
            #pragma unroll
            for (int kg = 0; kg < 4; ++kg)
                #pragma unroll
                for (int ks = 0; ks < 2; ++ks)
                    bk[kg][ks] = *(const bf16x8*)&Kc[(kg * 2 + ks) * 512 + lane * 8];

            f32x4 sc[2][4];
            __builtin_amdgcn_s_setprio(1);
            #pragma unroll
            for (int mt = 0; mt < 2; ++mt)
                #pragma unroll
                for (int kg = 0; kg < 4; ++kg) {
                    f32x4 z = {};
                    z = __builtin_amdgcn_mfma_f32_16x16x32_bf16(aq[mt][0], bk[kg][0], z, 0, 0, 0);
                    sc[mt][kg] = __builtin_amdgcn_mfma_f32_16x16x32_bf16(aq[mt][1], bk[kg][1], z, 0, 0, 0);
                }
            __builtin_amdgcn_s_setprio(0);

            if (kt >= nfull) {                    // diagonal tiles: causal mask
                #pragma unroll
                for (int mt = 0; mt < 2; ++mt)
                    #pragma unroll
                    for (int kg = 0; kg < 4; ++kg)
                        #pragma unroll
                        for (int r = 0; r < 4; ++r) {
                            int key = kbase + kg * 16 + col;
                            int qr  = q0 + mt * 16 + quad * 4 + r;
                            if (key > qr) sc[mt][kg][r] = NEGF;
                        }
            }

            #pragma unroll
            for (int mt = 0; mt < 2; ++mt)
                #pragma unroll
                for (int kg = 0; kg < 4; ++kg)
                    #pragma unroll
                    for (int r = 0; r < 4; ++r)
                        sc[mt][kg][r] = exp2_fast(sc[mt][kg][r]);

            #pragma unroll
            for (int mt = 0; mt < 2; ++mt)
                #pragma unroll
                for (int r = 0; r < 4; ++r)
                    lrow[mt][r] += (sc[mt][0][r] + sc[mt][1][r]) +
                                   (sc[mt][2][r] + sc[mt][3][r]);

            #pragma unroll
            for (int mt = 0; mt < 2; ++mt)
                #pragma unroll
                for (int kg = 0; kg < 4; ++kg)
                    #pragma unroll
                    for (int r = 0; r < 4; ++r)
                        Plw[mt * 1024 + pb[kg] + pq[r]] = t2bf(sc[mt][kg][r]);

            bf16x8 ap[2][2];
            #pragma unroll
            for (int mt = 0; mt < 2; ++mt)
                #pragma unroll
                for (int ks = 0; ks < 2; ++ks)
                    ap[mt][ks] = *(const bf16x8*)&Plw[(mt * 2 + ks) * 512 + ((lane * 8) ^ rsw)];

            __builtin_amdgcn_s_setprio(1);
            #pragma unroll
            for (int dc = 0; dc < 4; ++dc)
                #pragma unroll
                for (int ks = 0; ks < 2; ++ks) {
                    bf16x8 bv = *(const bf16x8*)&Vc[(dc * 2 + ks) * 512 + lane * 8];
                    oacc[0][dc] = __builtin_amdgcn_mfma_f32_16x16x32_bf16(ap[0][ks], bv, oacc[0][dc], 0, 0, 0);
                    oacc[1][dc] = __builtin_amdgcn_mfma_f32_16x16x32_bf16(ap[1][ks], bv, oacc[1][dc], 0, 0, 0);
                }
            __builtin_amdgcn_s_setprio(0);
        }
        asm volatile("s_waitcnt lgkmcnt(0)" ::: "memory");
        __builtin_amdgcn_sched_barrier(0);
        __builtin_amdgcn_s_barrier();
        __builtin_amdgcn_sched_barrier(0);
    }

    // single cross-lane reduction of row sums (rows live across the 16 col-lanes)
    #pragma unroll
    for (int d = 1; d < 16; d <<= 1)
        #pragma unroll
        for (int mt = 0; mt < 2; ++mt)
            #pragma unroll
            for (int r = 0; r < 4; ++r)
                lrow[mt][r] += __shfl_xor(lrow[mt][r], d);

    // epilogue: normalize, transpose via wave-private LDS, coalesced 16B stores
    unsigned short* Ol = Plw;                 // 2048 shorts = 32 rows x 64
    #pragma unroll
    for (int mt = 0; mt < 2; ++mt)
        #pragma unroll
        for (int r = 0; r < 4; ++r) {
            float inv = 1.0f / lrow[mt][r];
            int orow = (mt * 16 + quad * 4 + r) * 64;
            #pragma unroll
            for (int dc = 0; dc < 4; ++dc)
                Ol[orow + dc * 16 + col] = f2bf(oacc[mt][dc][r] * inv);
        }
    const int orw = lane >> 1, ohalf = lane & 1;
    unsigned short* og = Out + (size_t)(b * SEQ + q0 + orw) * DM + h * DK + ohalf * 32;
    #pragma unroll
    for (int s = 0; s < 4; ++s)
        *(uint4*)(og + s * 8) = *(const uint4*)&Ol[orw * 64 + ohalf * 32 + s * 8];
}

extern "C" void kernel_launch(void* const* d_in, const int* in_sizes, int n_in,
                              void* d_out, int out_size, void* d_ws, size_t ws_size,
                              hipStream_t stream) {
    // setup_inputs order: query, value, key, Wq, bq, Wk, bk, Wv, bv, Wo, bo
    const float* query = (const float*)d_in[0];
    const float* value = (const float*)d_in[1];
    const float* key   = (const float*)d_in[2];
    const float* Wq = (const float*)d_in[3];
    const float* bq = (const float*)d_in[4];
    const float* Wk = (const float*)d_in[5];
    const float* bk = (const float*)d_in[6];
    const float* Wv = (const float*)d_in[7];
    const float* bv = (const float*)d_in[8];
    const float* Wo = (const float*)d_in[9];
    const float* bo = (const float*)d_in[10];

    // Sequential-footprint layout (75MB, same as the reconciling R7 build):
    // R0-R2 = bf16 inputs, R3 = Q-proj; K/V projections live in d_out scratch
    // (32MB f32 buffer = 2 bf16 NELEM regions), which gemm_wo overwrites with
    // the final output AFTER attn has consumed them (stream-ordered).
    unsigned short* R0 = (unsigned short*)d_ws;
    unsigned short* R1 = R0 + NELEM;
    unsigned short* R2 = R1 + NELEM;
    unsigned short* R3 = R2 + NELEM;
    unsigned short* Wt = R3 + NELEM;
    unsigned short* Wto = Wt + 3 * (size_t)DM * DM;
    unsigned short* D0 = (unsigned short*)d_out;       // kws scratch
    unsigned short* D1 = D0 + NELEM;                   // vws scratch

    cvt_all<<<dim3(14336), 256, 0, stream>>>(query, key, value, Wq, Wk, Wv, Wo, R0, Wt);

    // fused QKV: Q->R3, K->D0 (d_out scratch), V->D1 (d_out scratch)
    gemm_qkv<<<dim3(8, 64, 3), 256, 0, stream>>>(R0, Wt, bq, bk, bv, R3, D0, D1);

    // attn reads R3/D0/D1, writes bf16 attn-out to R0 (inputs now dead)
    attn_mfma<<<dim3(BATCH * NH, SEQ / 128), 256, 0, stream>>>(R3, D0, D1, R0);

    // Wo reads R0, writes final f32 output over d_out (scratch now dead)
    gemm_wo<<<dim3(8, 128), 256, 0, stream>>>(R0, Wto, bo, (float*)d_out);
}